// Round 5
// baseline (350.874 us; speedup 1.0000x reference)
//
#include <hip/hip_runtime.h>
#include <hip/hip_bf16.h>
#include <math.h>

// AdaptGNN: B=8, N=2048, D=H=128, 3 layers.
// R5: agg restructured for 2 blocks/CU (512 thr, 45KB LDS, <=128 VGPR) with
// register-blocked MFMA (S-phase A m=32 persistent; O-phase 2x2 + K-split
// across wave pairs, single end-of-kernel LDS reduce).

typedef __attribute__((ext_vector_type(8))) short bf16x8;
typedef __attribute__((ext_vector_type(4))) short bf16x4;
typedef __attribute__((ext_vector_type(4))) float f32x4;

static constexpr int kB = 8, kN = 2048, kH = 128;

static __device__ __forceinline__ ushort bf16bits(float f) {
    __hip_bfloat16 hb = __float2bfloat16(f);
    return *reinterpret_cast<ushort*>(&hb);
}

// ---------------- x -> bf16 ----------------
__global__ __launch_bounds__(256) void cvt_bf16_kernel(
    const float* __restrict__ src, ushort* __restrict__ dst, int n4)
{
    int i = blockIdx.x * 256 + threadIdx.x;
    if (i >= n4) return;
    float4 v = ((const float4*)src)[i];
    bf16x4 o;
    o[0] = (short)bf16bits(v.x); o[1] = (short)bf16bits(v.y);
    o[2] = (short)bf16bits(v.z); o[3] = (short)bf16bits(v.w);
    ((bf16x4*)dst)[i] = o;
}

// WT[l][c][d] = bf16(W_l[d][c])
__global__ __launch_bounds__(256) void cvt_wT_kernel(
    const float* __restrict__ W0, const float* __restrict__ W1,
    const float* __restrict__ W2, ushort* __restrict__ WT)
{
    const float* W = blockIdx.y == 0 ? W0 : (blockIdx.y == 1 ? W1 : W2);
    int i = blockIdx.x * 256 + threadIdx.x;
    int d = i >> 7, c = i & 127;
    WT[(size_t)blockIdx.y * kH * kH + c * kH + d] = bf16bits(W[d * kH + c]);
}

// ---------------- linear (bf16 MFMA) + row-norm + transpose-out ----------------
__global__ __launch_bounds__(256) void linear_tr_kernel(
    const ushort* __restrict__ h16, const ushort* __restrict__ WT,
    const float* __restrict__ bias, ushort* __restrict__ t16,
    ushort* __restrict__ tT16, float* __restrict__ invn)
{
    __shared__ float ssb[64][2];
    __shared__ ushort tr[128 * 72];

    const int tid = threadIdx.x, lane = tid & 63, wid = tid >> 6;
    const int wr = wid >> 1, wc = wid & 1, quad = lane >> 4, l16 = lane & 15;
    const int rowbase = blockIdx.x * 64;
    const int b = rowbase / kN, q0 = rowbase % kN;

    f32x4 acc[2][4];
#pragma unroll
    for (int i = 0; i < 2; ++i)
#pragma unroll
        for (int ct = 0; ct < 4; ++ct) acc[i][ct] = (f32x4){0.f, 0.f, 0.f, 0.f};

#pragma unroll
    for (int k = 0; k < 4; ++k) {
        bf16x8 Af[2], Bf[4];
#pragma unroll
        for (int i = 0; i < 2; ++i)
            Af[i] = *(const bf16x8*)&h16[(size_t)(rowbase + wr * 32 + i * 16 + l16) * kH + k * 32 + quad * 8];
#pragma unroll
        for (int ct = 0; ct < 4; ++ct)
            Bf[ct] = *(const bf16x8*)&WT[(size_t)(wc * 64 + ct * 16 + l16) * kH + k * 32 + quad * 8];
#pragma unroll
        for (int i = 0; i < 2; ++i)
#pragma unroll
            for (int ct = 0; ct < 4; ++ct)
                acc[i][ct] = __builtin_amdgcn_mfma_f32_16x16x32_bf16(Af[i], Bf[ct], acc[i][ct], 0, 0, 0);
    }

    float bsr[4];
#pragma unroll
    for (int ct = 0; ct < 4; ++ct) bsr[ct] = bias[wc * 64 + ct * 16 + l16];

    f32x4 ss[2] = {(f32x4){0,0,0,0}, (f32x4){0,0,0,0}};
#pragma unroll
    for (int i = 0; i < 2; ++i)
#pragma unroll
        for (int ct = 0; ct < 4; ++ct)
#pragma unroll
            for (int r = 0; r < 4; ++r) {
                float v = acc[i][ct][r] + bsr[ct];
                acc[i][ct][r] = v;
                ss[i][r] += v * v;
            }
#pragma unroll
    for (int step = 1; step < 16; step <<= 1)
#pragma unroll
        for (int i = 0; i < 2; ++i)
#pragma unroll
            for (int r = 0; r < 4; ++r) ss[i][r] += __shfl_xor(ss[i][r], step);

    if (l16 == 0)
#pragma unroll
        for (int i = 0; i < 2; ++i)
#pragma unroll
            for (int r = 0; r < 4; ++r)
                ssb[wr * 32 + i * 16 + quad * 4 + r][wc] = ss[i][r];
    __syncthreads();
    if (tid < 64) {
        float s2 = ssb[tid][0] + ssb[tid][1];
        invn[rowbase + tid] = 1.f / fmaxf(sqrtf(s2), 1e-12f);
    }

#pragma unroll
    for (int i = 0; i < 2; ++i)
#pragma unroll
        for (int ct = 0; ct < 4; ++ct)
#pragma unroll
            for (int r = 0; r < 4; ++r) {
                const int pl = wr * 32 + i * 16 + quad * 4 + r;
                const int c = wc * 64 + ct * 16 + l16;
                ushort bits = bf16bits(acc[i][ct][r]);
                t16[(size_t)(rowbase + pl) * kH + c] = bits;
                tr[c * 72 + pl] = bits;
            }
    __syncthreads();

    ushort* tTb = tT16 + (size_t)b * kH * kN;
#pragma unroll
    for (int it = 0; it < 4; ++it) {
        int idx = tid + 256 * it;
        int c = idx >> 3, ch = idx & 7;
        bf16x8 v = *(const bf16x8*)&tr[c * 72 + ch * 8];
        *(bf16x8*)&tTb[(size_t)c * kN + q0 + ch * 8] = v;
    }
}

// ---------------- fused MFMA aggregation ----------------
// 512 thr = 8 waves. P-tile 64, q-tile 64.
// S-phase wave grid: wsp(2, p-half) x wsq(4, q-range 16); A m=32 persistent.
// O-phase wave grid: wop(2, p-half) x woc(2, c-half 64) x wok(2, K=q half 32).
// End: K-split partials reduced via LDS, stored by wok==0 waves.
__global__ __launch_bounds__(512, 4) void agg_kernel(
    const ushort* __restrict__ t, const ushort* __restrict__ tT,
    const float* __restrict__ invn, const float* __restrict__ ew,
    ushort* __restrict__ hout, float* __restrict__ fout, int last)
{
    __shared__ char smem[45312];
    ushort* TQ   = (ushort*)smem;            // [64][136]  17408 B
    ushort* TT   = (ushort*)(smem + 17408);  // [128][72]  18432 B
    ushort* Spm  = (ushort*)(smem + 35840);  // [64][72]    9216 B
    float* invPs = (float*)(smem + 45056);   // [64]
    float* redbuf = (float*)smem;            // overlay (k-reduce): 4 x [32][65]

    const int b = blockIdx.y, pbase = blockIdx.x * 64;
    const int tid = threadIdx.x, lane = tid & 63, wid = tid >> 6;
    const int quad = lane >> 4, l16 = lane & 15;
    const int wsp = wid >> 2, wsq = wid & 3;
    const int wop = wid >> 2, woc = (wid >> 1) & 1, wok = wid & 1;

    const ushort* tb  = t  + (size_t)b * kN * kH;
    const ushort* tTb = tT + (size_t)b * kH * kN;
    const float*  ewb = ew + (size_t)b * kN * kN;
    const float*  invb = invn + b * kN;

    if (tid < 64) invPs[tid] = invb[pbase + tid];

    // persistent S-phase A-frags: rows pbase + wsp*32 + it*16 + l16
    bf16x8 Af[2][4];
#pragma unroll
    for (int it = 0; it < 2; ++it)
#pragma unroll
        for (int k = 0; k < 4; ++k)
            Af[it][k] = *(const bf16x8*)&tb[(size_t)(pbase + wsp * 32 + it * 16 + l16) * kH + k * 32 + quad * 8];

    // staging maps (each thread: 32 B of TQ, 32 B of TT)
    const int qrow = tid >> 3, qoff = (tid & 7) * 16;
    const int trow = tid >> 2, toff = (tid & 3) * 16;

    bf16x8 rQ0 = *(const bf16x8*)&tb[(size_t)qrow * kH + qoff];
    bf16x8 rQ1 = *(const bf16x8*)&tb[(size_t)qrow * kH + qoff + 8];
    bf16x8 rT0 = *(const bf16x8*)&tTb[(size_t)trow * kN + toff];
    bf16x8 rT1 = *(const bf16x8*)&tTb[(size_t)trow * kN + toff + 8];

    const int ewq = wsq * 16 + l16;
    float ewc[2][4], invQc = invb[ewq];
#pragma unroll
    for (int it = 0; it < 2; ++it)
#pragma unroll
        for (int r = 0; r < 4; ++r)
            ewc[it][r] = ewb[(size_t)(pbase + wsp * 32 + it * 16 + quad * 4 + r) * kN + ewq];

    f32x4 oacc[2][4];
#pragma unroll
    for (int it = 0; it < 2; ++it)
#pragma unroll
        for (int ct = 0; ct < 4; ++ct) oacc[it][ct] = (f32x4){0.f, 0.f, 0.f, 0.f};

    __syncthreads();

    for (int qt = 0; qt < kN / 64; ++qt) {
        const int qbase = qt * 64;

        // publish staged tile
        *(bf16x8*)&TQ[qrow * 136 + qoff]     = rQ0;
        *(bf16x8*)&TQ[qrow * 136 + qoff + 8] = rQ1;
        *(bf16x8*)&TT[trow * 72 + toff]      = rT0;
        *(bf16x8*)&TT[trow * 72 + toff + 8]  = rT1;
        __syncthreads();

        // prefetch next tile
        float ewn[2][4] = {{0,0,0,0},{0,0,0,0}};
        float invQn = 0.f;
        if (qt + 1 < kN / 64) {
            const int qb2 = qbase + 64;
            rQ0 = *(const bf16x8*)&tb[(size_t)(qb2 + qrow) * kH + qoff];
            rQ1 = *(const bf16x8*)&tb[(size_t)(qb2 + qrow) * kH + qoff + 8];
            rT0 = *(const bf16x8*)&tTb[(size_t)trow * kN + qb2 + toff];
            rT1 = *(const bf16x8*)&tTb[(size_t)trow * kN + qb2 + toff + 8];
            invQn = invb[qb2 + ewq];
#pragma unroll
            for (int it = 0; it < 2; ++it)
#pragma unroll
                for (int r = 0; r < 4; ++r)
                    ewn[it][r] = ewb[(size_t)(pbase + wsp * 32 + it * 16 + quad * 4 + r) * kN + qb2 + ewq];
        }

        // ---- S-phase: dacc[it] = tP(m=32) . tQ(n=16, q=wsq*16)^T ----
        f32x4 dacc[2] = {(f32x4){0,0,0,0}, (f32x4){0,0,0,0}};
#pragma unroll
        for (int k = 0; k < 4; ++k) {
            bf16x8 Bf = *(const bf16x8*)&TQ[(wsq * 16 + l16) * 136 + k * 32 + quad * 8];
            dacc[0] = __builtin_amdgcn_mfma_f32_16x16x32_bf16(Af[0][k], Bf, dacc[0], 0, 0, 0);
            dacc[1] = __builtin_amdgcn_mfma_f32_16x16x32_bf16(Af[1][k], Bf, dacc[1], 0, 0, 0);
        }
        // S' = dacc * ew * invQ -> bf16 -> Spm
#pragma unroll
        for (int it = 0; it < 2; ++it)
#pragma unroll
            for (int r = 0; r < 4; ++r)
                Spm[(wsp * 32 + it * 16 + quad * 4 + r) * 72 + wsq * 16 + l16] =
                    bf16bits(dacc[it][r] * ewc[it][r] * invQc);
        __syncthreads();

        // ---- O-phase (K-split): oacc += S'[p, wok*32+k] @ t[wok*32+k, c] ----
        bf16x8 Sa[2];
#pragma unroll
        for (int it = 0; it < 2; ++it)
            Sa[it] = *(const bf16x8*)&Spm[(wop * 32 + it * 16 + l16) * 72 + wok * 32 + quad * 8];
#pragma unroll
        for (int ct = 0; ct < 4; ++ct) {
            bf16x8 Bb = *(const bf16x8*)&TT[(woc * 64 + ct * 16 + l16) * 72 + wok * 32 + quad * 8];
            oacc[0][ct] = __builtin_amdgcn_mfma_f32_16x16x32_bf16(Sa[0], Bb, oacc[0][ct], 0, 0, 0);
            oacc[1][ct] = __builtin_amdgcn_mfma_f32_16x16x32_bf16(Sa[1], Bb, oacc[1][ct], 0, 0, 0);
        }
        __syncthreads();

#pragma unroll
        for (int it = 0; it < 2; ++it) {
            invQc = invQn;
#pragma unroll
            for (int r = 0; r < 4; ++r) ewc[it][r] = ewn[it][r];
        }
    }

    // ---- K-split reduce + store ----
    if (wok == 1) {
        float* rb = redbuf + (wop * 2 + woc) * 2080;
#pragma unroll
        for (int it = 0; it < 2; ++it)
#pragma unroll
            for (int ct = 0; ct < 4; ++ct)
#pragma unroll
                for (int r = 0; r < 4; ++r)
                    rb[(it * 16 + quad * 4 + r) * 65 + ct * 16 + l16] = oacc[it][ct][r];
    }
    __syncthreads();
    if (wok == 0) {
        float* rb = redbuf + (wop * 2 + woc) * 2080;
#pragma unroll
        for (int it = 0; it < 2; ++it)
#pragma unroll
            for (int ct = 0; ct < 4; ++ct)
#pragma unroll
                for (int r = 0; r < 4; ++r) {
                    const int pl = wop * 32 + it * 16 + quad * 4 + r;
                    const int p = pbase + pl;
                    const int c = woc * 64 + ct * 16 + l16;
                    float v = (oacc[it][ct][r] + rb[(it * 16 + quad * 4 + r) * 65 + ct * 16 + l16]) * invPs[pl];
                    if (!last) {
                        hout[(size_t)b * kN * kH + (size_t)p * kH + c] = bf16bits(fmaxf(v, 0.f));
                    } else {
                        fout[(size_t)b * kN * kH + (size_t)p * kH + c] = v;
                    }
                }
    }
}

extern "C" void kernel_launch(void* const* d_in, const int* in_sizes, int n_in,
                              void* d_out, int out_size, void* d_ws, size_t ws_size,
                              hipStream_t stream) {
    const float* x  = (const float*)d_in[0];
    const float* ew = (const float*)d_in[1];
    const float* W0 = (const float*)d_in[2];
    const float* b0 = (const float*)d_in[3];
    const float* W1 = (const float*)d_in[4];
    const float* b1 = (const float*)d_in[5];
    const float* W2 = (const float*)d_in[6];
    const float* b2 = (const float*)d_in[7];
    const float* bias[3] = {b0, b1, b2};

    const size_t nBNH = (size_t)kB * kN * kH;
    ushort* h16  = (ushort*)d_ws;
    ushort* t16  = h16 + nBNH;
    ushort* tT16 = t16 + nBNH;
    float*  invn = (float*)(tT16 + nBNH);
    ushort* WT   = (ushort*)(invn + (size_t)kB * kN);
    float*  out  = (float*)d_out;

    cvt_bf16_kernel<<<(int)(nBNH / 4 + 255) / 256, 256, 0, stream>>>(x, h16, (int)(nBNH / 4));
    cvt_wT_kernel<<<dim3(64, 3), 256, 0, stream>>>(W0, W1, W2, WT);

    for (int layer = 0; layer < 3; ++layer) {
        linear_tr_kernel<<<kB * kN / 64, 256, 0, stream>>>(
            h16, WT + (size_t)layer * kH * kH, bias[layer], t16, tT16, invn);
        agg_kernel<<<dim3(kN / 64, kB), 512, 0, stream>>>(
            t16, tT16, invn, ew, h16, out, layer == 2 ? 1 : 0);
    }
}